// Round 2
// baseline (540.614 us; speedup 1.0000x reference)
//
#include <hip/hip_runtime.h>
#include <math.h>

// x = (16, 32, 65536) fp32.  512 independent rows of 65536 -> one block per row.
// Single fused kernel: sum1 -> thr1 -> apply1 -> sum2 -> thr2 -> apply2 (in-place),
// everything block-local (std is per-row), only __syncthreads() between phases.
#define LROW   65536
#define NROWS  512
#define NT     512               // threads per block (8 waves)
#define CK     8192              // chunk staged in LDS per iteration
#define NC     (LROW / CK)       // 8 chunk iterations per pass
#define EPT    (CK / NT)         // 16 elements per thread
#define V4     (CK / 4 / NT)     // 4 float4 loads per thread per chunk
#define HALO   5
#define NEL    (CK + 2 * HALO)

#define TREND_SCALING       0.6f
#define DETAIL_PRESERVATION 0.85f
#define SPIKE_DAMPING       0.35f

// LDS swizzle: per-thread stride-16 fragments would be 32-way conflicted;
// phys = i + i/16 -> per-lane stride 17 (odd) -> 2 lanes/bank = free (m136).
__device__ __forceinline__ int sw(int i) { return i + (i >> 4); }
__device__ __forceinline__ int refl(int g) {
    return g < 0 ? -g : (g >= LROW ? 2 * LROW - 2 - g : g);
}

struct Pref { float4 m[V4]; float h; };

// Issue global loads for chunk c into registers (coalesced float4 + halo scalar).
// loadLeft=false skips the left-halo global load (in-place pass uses LDS carry).
__device__ __forceinline__ void issue(const float* rowp, int c, int tid, Pref& p,
                                      bool loadLeft) {
    const float4* s4 = (const float4*)(rowp + c * CK);
#pragma unroll
    for (int i = 0; i < V4; i++) p.m[i] = s4[tid + i * NT];
    if (tid < 10) {
        if (tid >= 5 || loadLeft) {
            int l = (tid < 5) ? tid : CK + tid;   // logical halo slot
            int g = c * CK - HALO + l;            // global position
            p.h = rowp[refl(g)];
        }
    }
}

__device__ __forceinline__ void stage(float* buf, int tid, const Pref& p,
                                      const float* carryL, bool useCarry) {
#pragma unroll
    for (int i = 0; i < V4; i++) {
        int l = (tid + i * NT) * 4 + HALO;
        buf[sw(l)]     = p.m[i].x;
        buf[sw(l + 1)] = p.m[i].y;
        buf[sw(l + 2)] = p.m[i].z;
        buf[sw(l + 3)] = p.m[i].w;
    }
    if (tid < 10) {
        int l = (tid < 5) ? tid : CK + tid;
        float v = (useCarry && tid < 5) ? carryL[tid] : p.h;
        buf[sw(l)] = v;
    }
}

__global__ __launch_bounds__(NT, 4) void fused_denoise(
        const float* __restrict__ x, float* out,
        const float* __restrict__ k5p, const float* __restrict__ k11p) {
    __shared__ float  buf[NEL + (NEL >> 4) + 2];   // ~34.9 KB swizzled staging
    __shared__ double red[(NT / 64) * 2];
    __shared__ float  smThr;
    __shared__ float  carry[8];

    const int row = blockIdx.x;
    const int tid = threadIdx.x;
    const float* xr  = x + (size_t)row * LROW;
    float*       orow = out + (size_t)row * LROW;
    const float w5  = k5p[0];
    const float w11 = k11p[0];

    // ---- per-row std pass: threshold = max(std(r, ddof=1), 1e-6) * 3.5 ----
    auto sum_pass = [&](const float* src) -> float {
        double s = 0.0, q = 0.0;
        Pref pA, pB;
        issue(src, 0, tid, pA, true);
        for (int c = 0; c < NC; c++) {
            Pref& cur = (c & 1) ? pB : pA;
            Pref& nxt = (c & 1) ? pA : pB;
            if (c + 1 < NC) issue(src, c + 1, tid, nxt, true);
            __syncthreads();                       // prior compute done with buf
            stage(buf, tid, cur, nullptr, false);
            __syncthreads();
            float v[EPT + 2 * HALO];
            const int base = tid * EPT;
#pragma unroll
            for (int j = 0; j < EPT + 2 * HALO; j++) v[j] = buf[sw(base + j)];
#pragma unroll
            for (int k = 0; k < EPT; k++) {
                float lac = 0.f;
#pragma unroll
                for (int d = 0; d < 5; d++) lac = fmaf(v[k + 3 + d], w5, lac);
                float r = v[k + HALO] - lac;
                s += (double)r;
                q += (double)r * (double)r;
            }
        }
        // deterministic reduction: wave butterfly -> 8 wave partials -> serial
#pragma unroll
        for (int off = 32; off > 0; off >>= 1) {
            s += __shfl_down(s, off);
            q += __shfl_down(q, off);
        }
        const int wid = tid >> 6, lane = tid & 63;
        if (lane == 0) { red[2 * wid] = s; red[2 * wid + 1] = q; }
        __syncthreads();
        if (tid == 0) {
            double S = 0.0, Q = 0.0;
            for (int w = 0; w < NT / 64; w++) { S += red[2 * w]; Q += red[2 * w + 1]; }
            const double N = (double)LROW;
            double var = (Q - S * S / N) / (N - 1.0);
            if (var < 0.0) var = 0.0;
            smThr = fmaxf((float)sqrt(var), 1e-6f) * 3.5f;
        }
        __syncthreads();
        return smThr;
    };

    // ---- apply pass: damp spikes, recombine, write dst row ----
    // inplace: src == dst. Left halo for chunk c+1 comes from the LDS carry
    // (original values saved before overwrite); right-halo / main prefetch loads
    // are consumed strictly before their producer chunk's stores are issued.
    auto apply_pass = [&](const float* src, float th, bool inplace) {
        Pref pA, pB;
        issue(src, 0, tid, pA, true);
        for (int c = 0; c < NC; c++) {
            Pref& cur = (c & 1) ? pB : pA;
            Pref& nxt = (c & 1) ? pA : pB;
            if (c + 1 < NC) issue(src, c + 1, tid, nxt, !inplace);
            __syncthreads();
            stage(buf, tid, cur, carry, inplace && c > 0);
            __syncthreads();
            float v[EPT + 2 * HALO];
            const int base = tid * EPT;
#pragma unroll
            for (int j = 0; j < EPT + 2 * HALO; j++) v[j] = buf[sw(base + j)];
            if (inplace && tid < 5) carry[tid] = buf[sw(CK + tid)];  // original tail
            float o[EPT];
#pragma unroll
            for (int k = 0; k < EPT; k++) {
                float lac = 0.f, tac = 0.f;
#pragma unroll
                for (int d = 0; d < 5; d++) lac = fmaf(v[k + 3 + d], w5, lac);
#pragma unroll
                for (int d = 0; d < 11; d++) tac = fmaf(v[k + d], w11, tac);
                float cv = v[k + HALO];
                float r = cv - lac;
                r = (fabsf(r) > th) ? r * SPIKE_DAMPING : r;
                o[k] = (1.0f - TREND_SCALING) * lac + TREND_SCALING * tac +
                       DETAIL_PRESERVATION * r;
            }
            float4* d4 = (float4*)(orow + c * CK + tid * EPT);
#pragma unroll
            for (int k4 = 0; k4 < EPT / 4; k4++)
                d4[k4] = make_float4(o[4 * k4], o[4 * k4 + 1],
                                     o[4 * k4 + 2], o[4 * k4 + 3]);
        }
    };

    float th1 = sum_pass(xr);
    apply_pass(xr, th1, false);
    __syncthreads();           // drain apply1 stores before re-reading out
    float th2 = sum_pass(orow);
    apply_pass(orow, th2, true);
}

extern "C" void kernel_launch(void* const* d_in, const int* in_sizes, int n_in,
                              void* d_out, int out_size, void* d_ws, size_t ws_size,
                              hipStream_t stream) {
    const float* x   = (const float*)d_in[0];
    const float* k5  = (const float*)d_in[1];
    const float* k11 = (const float*)d_in[2];
    float* out = (float*)d_out;
    hipLaunchKernelGGL(fused_denoise, dim3(NROWS), dim3(NT), 0, stream,
                       x, out, k5, k11);
}

// Round 4
// 363.620 us; speedup vs baseline: 1.4868x; 1.4868x over previous
//
#include <hip/hip_runtime.h>
#include <math.h>

// x = (16, 32, 65536) fp32. Per-row std -> threshold -> damp -> recombine, x2.
// Structure (5 launches, zero LDS / zero barriers in the big kernels):
//   k_stats1 (read x)            -> per-wave partials of (r1, r1^2)
//   k_thr                        -> th1[512]
//   k_apply1 (read x, write ws)  -> cur2 = iter1(x); fused stats of r2
//   k_thr                        -> th2[512]
//   k_apply2 (read ws, write out)-> final = iter2(cur2), nontemporal stores
// Each thread owns 8 contiguous floats; halos come from overlapping float4
// loads (L1/L2 absorb the overlap; HBM lines fetched once).

#define LROW  65536
#define NROWS 512
#define NT    256
#define TPE   8                      // elements per thread
#define EPB   (NT * TPE)             // 2048 elements per block
#define BPR   (LROW / EPB)           // 32 blocks per row
#define GRID  (NROWS * BPR)          // 16384 blocks
#define WPB   (NT / 64)              // 4 waves per block
#define PPR   (BPR * WPB)            // 128 partials per row

#define TS 0.6f
#define DP 0.85f
#define SD 0.35f

typedef float floatx4 __attribute__((ext_vector_type(4)));

__device__ __forceinline__ int refl(int g) {
    return g < 0 ? -g : (g >= LROW ? 2 * LROW - 2 - g : g);
}

__device__ __forceinline__ void wave_reduce_store(double s, double q, int tid,
                                                  int bid, double2* parts) {
#pragma unroll
    for (int off = 32; off; off >>= 1) {
        s += __shfl_down(s, off);
        q += __shfl_down(q, off);
    }
    if ((tid & 63) == 0) {
        double2 v; v.x = s; v.y = q;
        parts[(size_t)bid * WPB + (tid >> 6)] = v;
    }
}

// ---- pass 1: stats of r1 = x - local5(x) (halo 2 -> 16 floats/thread) ----
__global__ __launch_bounds__(NT) void k_stats1(const float* __restrict__ x,
                                               const float* __restrict__ k5p,
                                               double2* __restrict__ parts) {
    const int bid = blockIdx.x, tid = threadIdx.x;
    const int row = bid / BPR, ck = bid % BPR;
    const float* rp = x + (size_t)row * LROW;
    const int t = ck * EPB + tid * TPE;
    const float w5 = k5p[0];

    float f[16];  // x[t-4 .. t+11]
    if (t >= 4 && t + 12 <= LROW) {
        const float4* p4 = (const float4*)(rp + t - 4);
#pragma unroll
        for (int i = 0; i < 4; i++) {
            float4 u = p4[i];
            f[4 * i] = u.x; f[4 * i + 1] = u.y; f[4 * i + 2] = u.z; f[4 * i + 3] = u.w;
        }
    } else {
#pragma unroll
        for (int i = 0; i < 16; i++) f[i] = rp[refl(t - 4 + i)];
    }

    double s = 0.0, q = 0.0;
#pragma unroll
    for (int k = 0; k < TPE; k++) {
        float loc = 0.f;
#pragma unroll
        for (int d = 0; d < 5; d++) loc = fmaf(f[k + 2 + d], w5, loc);
        float r = f[k + 4] - loc;
        s += (double)r;
        q += (double)r * (double)r;
    }
    wave_reduce_store(s, q, tid, bid, parts);
}

// ---- tiny: per-row threshold = max(std(ddof=1), 1e-6) * 3.5 (deterministic) ----
__global__ void k_thr(const double2* __restrict__ parts, float* __restrict__ th) {
    int r = blockIdx.x * blockDim.x + threadIdx.x;
    if (r >= NROWS) return;
    const double2* p = parts + (size_t)r * PPR;
    double S = 0.0, Q = 0.0;
    for (int i = 0; i < PPR; i++) { S += p[i].x; Q += p[i].y; }
    const double N = (double)LROW;
    double var = (Q - S * S / N) / (N - 1.0);
    if (var < 0.0) var = 0.0;
    th[r] = fmaxf((float)sqrt(var), 1e-6f) * 3.5f;
}

// ---- pass 2: cur2 = iter1(x) on ext positions [t-2, t+9]; fused stats of
//      r2 = cur2 - local5(cur2). x halo 7 -> 24 floats/thread. ----
__global__ __launch_bounds__(NT) void k_apply1(const float* __restrict__ x,
                                               float* __restrict__ cur2,
                                               const float* __restrict__ k5p,
                                               const float* __restrict__ k11p,
                                               const float* __restrict__ th1,
                                               double2* __restrict__ parts2) {
    const int bid = blockIdx.x, tid = threadIdx.x;
    const int row = bid / BPR, ck = bid % BPR;
    const float* rp = x + (size_t)row * LROW;
    const int t = ck * EPB + tid * TPE;
    const float w5 = k5p[0], w11 = k11p[0], th = th1[row];

    float f[24];  // x[t-8 .. t+15]
    if (t >= 8 && t + 16 <= LROW) {
        const float4* p4 = (const float4*)(rp + t - 8);
#pragma unroll
        for (int i = 0; i < 6; i++) {
            float4 u = p4[i];
            f[4 * i] = u.x; f[4 * i + 1] = u.y; f[4 * i + 2] = u.z; f[4 * i + 3] = u.w;
        }
    } else {
#pragma unroll
        for (int i = 0; i < 24; i++) f[i] = rp[refl(t - 8 + i)];
    }

    // cur2 at positions p = t-2+j, j in [0,12): needs x[p-5..p+5] = f[j+1..j+11]
    float c2[12];
#pragma unroll
    for (int j = 0; j < 12; j++) {
        float trend = 0.f, loc = 0.f;
#pragma unroll
        for (int d = 0; d < 11; d++) trend = fmaf(f[j + 1 + d], w11, trend);
#pragma unroll
        for (int d = 0; d < 5; d++) loc = fmaf(f[j + 4 + d], w5, loc);
        float r = f[j + 6] - loc;
        r = (fabsf(r) > th) ? r * SD : r;
        c2[j] = (1.0f - TS) * loc + TS * trend + DP * r;
    }

    // stats of r2 over the 8 owned positions (center c2[k+2])
    double s = 0.0, q = 0.0;
#pragma unroll
    for (int k = 0; k < TPE; k++) {
        float loc = 0.f;
#pragma unroll
        for (int d = 0; d < 5; d++) loc = fmaf(c2[k + d], w5, loc);
        float r = c2[k + 2] - loc;
        s += (double)r;
        q += (double)r * (double)r;
    }

    float* op = cur2 + (size_t)row * LROW + t;
    ((float4*)op)[0] = make_float4(c2[2], c2[3], c2[4], c2[5]);
    ((float4*)op)[1] = make_float4(c2[6], c2[7], c2[8], c2[9]);

    wave_reduce_store(s, q, tid, bid, parts2);
}

// ---- pass 3: final = iter2(cur2). cur2 halo 5 -> 24 floats/thread.
//      ws -> d_out, no aliasing; nontemporal final stores. ----
__global__ __launch_bounds__(NT) void k_apply2(const float* __restrict__ cur2,
                                               float* __restrict__ out,
                                               const float* __restrict__ k5p,
                                               const float* __restrict__ k11p,
                                               const float* __restrict__ th2) {
    const int bid = blockIdx.x, tid = threadIdx.x;
    const int row = bid / BPR, ck = bid % BPR;
    const float* rp = cur2 + (size_t)row * LROW;
    const int t = ck * EPB + tid * TPE;
    const float w5 = k5p[0], w11 = k11p[0], th = th2[row];

    float f[24];  // cur2[t-8 .. t+15]
    if (t >= 8 && t + 16 <= LROW) {
        const float4* p4 = (const float4*)(rp + t - 8);
#pragma unroll
        for (int i = 0; i < 6; i++) {
            float4 u = p4[i];
            f[4 * i] = u.x; f[4 * i + 1] = u.y; f[4 * i + 2] = u.z; f[4 * i + 3] = u.w;
        }
    } else {
#pragma unroll
        for (int i = 0; i < 24; i++) f[i] = rp[refl(t - 8 + i)];
    }

    float o[TPE];
#pragma unroll
    for (int k = 0; k < TPE; k++) {
        float trend = 0.f, loc = 0.f;
#pragma unroll
        for (int d = 0; d < 11; d++) trend = fmaf(f[k + 3 + d], w11, trend);
#pragma unroll
        for (int d = 0; d < 5; d++) loc = fmaf(f[k + 6 + d], w5, loc);
        float r = f[k + 8] - loc;
        r = (fabsf(r) > th) ? r * SD : r;
        o[k] = (1.0f - TS) * loc + TS * trend + DP * r;
    }

    // nontemporal final stores: out is write-once, keep cur2/x resident in L3.
    floatx4* op = (floatx4*)(out + (size_t)row * LROW + t);
    floatx4 v0 = { o[0], o[1], o[2], o[3] };
    floatx4 v1 = { o[4], o[5], o[6], o[7] };
    __builtin_nontemporal_store(v0, op);
    __builtin_nontemporal_store(v1, op + 1);
}

extern "C" void kernel_launch(void* const* d_in, const int* in_sizes, int n_in,
                              void* d_out, int out_size, void* d_ws, size_t ws_size,
                              hipStream_t stream) {
    const float* x   = (const float*)d_in[0];
    const float* k5  = (const float*)d_in[1];
    const float* k11 = (const float*)d_in[2];
    float* out = (float*)d_out;

    // ws layout: cur2 (128 MiB) | parts1 (1 MiB) | parts2 (1 MiB) | th1 | th2
    float*   cur2 = (float*)d_ws;
    double2* p1   = (double2*)((char*)d_ws + (size_t)LROW * NROWS * 4);
    double2* p2   = p1 + (size_t)GRID * WPB;
    float*   th1  = (float*)(p2 + (size_t)GRID * WPB);
    float*   th2  = th1 + NROWS;

    hipLaunchKernelGGL(k_stats1, dim3(GRID), dim3(NT), 0, stream, x, k5, p1);
    hipLaunchKernelGGL(k_thr, dim3(1), dim3(NROWS), 0, stream, p1, th1);
    hipLaunchKernelGGL(k_apply1, dim3(GRID), dim3(NT), 0, stream,
                       x, cur2, k5, k11, th1, p2);
    hipLaunchKernelGGL(k_thr, dim3(1), dim3(NROWS), 0, stream, p2, th2);
    hipLaunchKernelGGL(k_apply2, dim3(GRID), dim3(NT), 0, stream,
                       cur2, out, k5, k11, th2);
}